// Round 1
// baseline (627.060 us; speedup 1.0000x reference)
//
#include <hip/hip_runtime.h>
#include <math.h>

// ---------------- constants ----------------
// N=50000, E=800000, IN=128, H1=256 (8 heads x 32), H2=64, OUT=128
#define NEG_SLOPE 0.2f
#define BN_EPS 1e-5f

__device__ __forceinline__ float elu_f(float x){ return x > 0.f ? x : expm1f(x); }
__device__ __forceinline__ float lrelu_f(float x){ return x > 0.f ? x : NEG_SLOPE * x; }

// ---------------- dtype detect (int64 vs int32 edge_index) ----------------
__global__ void detect_dtype_kernel(const void* ei, int n_check, long long N, int* flag64)
{
    __shared__ int ok_s;
    int t = threadIdx.x;
    if (t == 0) ok_s = 1;
    __syncthreads();
    const long long* p = (const long long*)ei;
    for (int i = t; i < n_check; i += blockDim.x) {
        long long v = p[i];
        if (v < 0 || v >= N) ok_s = 0;   // benign race: everyone writes 0
    }
    __syncthreads();
    if (t == 0) *flag64 = ok_s;
}

__device__ __forceinline__ void get_edge(const void* ei, int e, int E, int f64, int& s, int& d)
{
    if (e < E) {
        if (f64) { const long long* p = (const long long*)ei; s = (int)p[e]; d = (int)p[E + e]; }
        else     { const int*       p = (const int*)ei;       s = p[e];      d = p[E + e]; }
    } else {
        s = d = e - E;   // self loops appended
    }
}

// ---------------- CSR build ----------------
__global__ void count_kernel(const void* ei, int E, int N, const int* flag64, int* deg)
{
    int i = blockIdx.x * blockDim.x + threadIdx.x;
    int ET = E + N;
    if (i >= ET) return;
    int s, d;
    get_edge(ei, i, E, *flag64, s, d);
    atomicAdd(&deg[d], 1);
}

// single block, 1024 threads; deg and fillptr are the SAME buffer (in-place)
__global__ void scan_kernel(int* deg_fill, int* rowptr, int N)
{
    __shared__ int sums[1024];
    __shared__ int offs[1024];
    int t = threadIdx.x;
    int chunk = (N + 1023) / 1024;
    int b = t * chunk;
    int e = min(N, b + chunk);
    int s = 0;
    for (int i = b; i < e; ++i) s += deg_fill[i];
    sums[t] = s;
    __syncthreads();
    if (t == 0) { int r = 0; for (int i = 0; i < 1024; ++i) { offs[i] = r; r += sums[i]; } }
    __syncthreads();
    int pref = offs[t];
    for (int i = b; i < e; ++i) {
        int d = deg_fill[i];       // read before overwrite (same thread owns chunk)
        rowptr[i] = pref;
        deg_fill[i] = pref;        // becomes fill cursor
        pref += d;
    }
    if (t == 1023) rowptr[N] = pref;
}

__global__ void fill_kernel(const void* ei, int E, int N, const int* flag64,
                            int* fillptr, int* esrc)
{
    int i = blockIdx.x * blockDim.x + threadIdx.x;
    int ET = E + N;
    if (i >= ET) return;
    int s, d;
    get_edge(ei, i, E, *flag64, s, d);
    int pos = atomicAdd(&fillptr[d], 1);
    esrc[pos] = s;
}

// ---------------- BN fold precompute ----------------
// S = g*rsqrt(v+eps); C = b*S + be - m*S   (bias b applied before BN)
__global__ void precompute_kernel(const float* b1, const float* b2, const float* bp,
    const float* g1, const float* be1, const float* m1, const float* v1,
    const float* g2, const float* be2, const float* m2, const float* v2,
    const float* g3, const float* be3, const float* m3, const float* v3,
    float* par)
{
    int t = threadIdx.x;
    if (t < 256) { float s = g1[t] * rsqrtf(v1[t] + BN_EPS); par[t] = s;        par[256 + t] = b1[t] * s + be1[t] - m1[t] * s; }
    if (t < 64)  { float s = g2[t] * rsqrtf(v2[t] + BN_EPS); par[512 + t] = s;  par[576 + t] = b2[t] * s + be2[t] - m2[t] * s; }
    if (t < 128) { float s = g3[t] * rsqrtf(v3[t] + BN_EPS); par[640 + t] = s;  par[768 + t] = bp[t] * s + be3[t] - m3[t] * s; }
}

// ---------------- tiled fp32 GEMM: C[M,NC] = A[M,K] @ B[K,NC] ----------------
// optional per-column epilogue y = acc*S[col] + C[col]
__global__ void gemm64_kernel(const float* __restrict__ A, const float* __restrict__ B,
                              float* __restrict__ C, int M, int K, int NC,
                              const float* __restrict__ S, const float* __restrict__ Cc)
{
    const int BM = 64, BN = 64, BK = 32;
    __shared__ float As[BK][BM + 1];            // transposed: As[k][m]
    __shared__ __align__(16) float Bs[BK][BN];
    int tx = threadIdx.x & 15, ty = threadIdx.x >> 4;
    int m0 = blockIdx.x * BM, n0 = blockIdx.y * BN;
    float acc[4][4] = {};

    for (int k0 = 0; k0 < K; k0 += BK) {
        #pragma unroll
        for (int p = 0; p < (BM * BK) / 256; ++p) {
            int idx = threadIdx.x + p * 256;
            int m = idx >> 5, k = idx & 31;
            int gm = m0 + m;
            As[k][m] = (gm < M) ? A[(size_t)gm * K + k0 + k] : 0.f;
        }
        #pragma unroll
        for (int p = 0; p < (BK * BN) / 256; ++p) {
            int idx = threadIdx.x + p * 256;
            int k = idx >> 6, n = idx & 63;
            Bs[k][n] = B[(size_t)(k0 + k) * NC + n0 + n];
        }
        __syncthreads();
        #pragma unroll
        for (int kk = 0; kk < BK; ++kk) {
            float4 b = *reinterpret_cast<const float4*>(&Bs[kk][tx * 4]);
            float a[4];
            #pragma unroll
            for (int i = 0; i < 4; ++i) a[i] = As[kk][ty * 4 + i];
            #pragma unroll
            for (int i = 0; i < 4; ++i) {
                acc[i][0] += a[i] * b.x;
                acc[i][1] += a[i] * b.y;
                acc[i][2] += a[i] * b.z;
                acc[i][3] += a[i] * b.w;
            }
        }
        __syncthreads();
    }
    #pragma unroll
    for (int i = 0; i < 4; ++i) {
        int gm = m0 + ty * 4 + i;
        if (gm >= M) continue;
        int gc = n0 + tx * 4;
        float4 v = make_float4(acc[i][0], acc[i][1], acc[i][2], acc[i][3]);
        if (S) {
            v.x = v.x * S[gc + 0] + Cc[gc + 0];
            v.y = v.y * S[gc + 1] + Cc[gc + 1];
            v.z = v.z * S[gc + 2] + Cc[gc + 2];
            v.w = v.w * S[gc + 3] + Cc[gc + 3];
        }
        *reinterpret_cast<float4*>(&C[(size_t)gm * NC + gc]) = v;
    }
}

// ---------------- attention coefficients layer 1 ----------------
// a_s[n,h] = sum_{o} h1[n,h*32+o]*att_src[h*32+o]  -> flat dot per 32-thread group
__global__ void att1_kernel(const float* __restrict__ h1,
                            const float* __restrict__ a_src, const float* __restrict__ a_dst,
                            float* __restrict__ as1, float* __restrict__ ad1, int N)
{
    int n = blockIdx.x;
    int t = threadIdx.x;          // 256
    float v = h1[(size_t)n * 256 + t];
    float s = v * a_src[t];
    float d = v * a_dst[t];
    #pragma unroll
    for (int off = 16; off; off >>= 1) {
        s += __shfl_down(s, off, 32);
        d += __shfl_down(d, off, 32);
    }
    if ((t & 31) == 0) {
        as1[n * 8 + (t >> 5)] = s;
        ad1[n * 8 + (t >> 5)] = d;
    }
}

// ---------------- attention coefficients layer 2 ----------------
__global__ void att2_kernel(const float* __restrict__ h2,
                            const float* __restrict__ a_src, const float* __restrict__ a_dst,
                            float* __restrict__ as2, float* __restrict__ ad2, int N)
{
    int wid = (blockIdx.x * blockDim.x + threadIdx.x) >> 6;
    int lane = threadIdx.x & 63;
    if (wid >= N) return;
    float v = h2[(size_t)wid * 64 + lane];
    float s = v * a_src[lane];
    float d = v * a_dst[lane];
    #pragma unroll
    for (int off = 32; off; off >>= 1) {
        s += __shfl_down(s, off, 64);
        d += __shfl_down(d, off, 64);
    }
    if (lane == 0) { as2[wid] = s; ad2[wid] = d; }
}

// ---------------- aggregation layer 1: wave per node ----------------
// lane l owns features 4l..4l+3 -> single head (4l)>>5 = l>>3
// out = ELU( (num/den) * S1[f] + C1[f] )
__global__ void agg1_kernel(const float* __restrict__ h1,
                            const float* __restrict__ as1, const float* __restrict__ ad1,
                            const int* __restrict__ rowptr, const int* __restrict__ esrc,
                            const float* __restrict__ par,
                            float* __restrict__ outb, int N)
{
    int wid = (blockIdx.x * blockDim.x + threadIdx.x) >> 6;
    int lane = threadIdx.x & 63;
    if (wid >= N) return;
    int n = wid;
    float ad = ad1[n * 8 + (lane & 7)];
    int beg = rowptr[n], end = rowptr[n + 1];
    float4 acc = make_float4(0.f, 0.f, 0.f, 0.f);
    float den = 0.f;
    int hsrc = lane >> 3;   // shfl source lane holding this lane's head weight
    for (int i = beg; i < end; ++i) {
        int src = esrc[i];
        float as = as1[src * 8 + (lane & 7)];
        float w = __expf(lrelu_f(as + ad));
        den += w;                                   // lane l accumulates head (l&7)
        float wl = __shfl(w, hsrc, 64);
        float4 hv = *reinterpret_cast<const float4*>(&h1[(size_t)src * 256 + lane * 4]);
        acc.x += wl * hv.x;
        acc.y += wl * hv.y;
        acc.z += wl * hv.z;
        acc.w += wl * hv.w;
    }
    float dh = __shfl(den, hsrc, 64);
    float inv = 1.f / (dh + 1e-16f);
    int f0 = lane * 4;
    const float* S1 = par;
    const float* C1 = par + 256;
    float4 o;
    o.x = elu_f(acc.x * inv * S1[f0 + 0] + C1[f0 + 0]);
    o.y = elu_f(acc.y * inv * S1[f0 + 1] + C1[f0 + 1]);
    o.z = elu_f(acc.z * inv * S1[f0 + 2] + C1[f0 + 2]);
    o.w = elu_f(acc.w * inv * S1[f0 + 3] + C1[f0 + 3]);
    *reinterpret_cast<float4*>(&outb[(size_t)n * 256 + f0]) = o;
}

// ---------------- aggregation layer 2: wave per node, 1 head, 64 feats ----------------
__global__ void agg2_kernel(const float* __restrict__ h2,
                            const float* __restrict__ as2, const float* __restrict__ ad2,
                            const int* __restrict__ rowptr, const int* __restrict__ esrc,
                            const float* __restrict__ par,
                            float* __restrict__ outb, int N)
{
    int wid = (blockIdx.x * blockDim.x + threadIdx.x) >> 6;
    int lane = threadIdx.x & 63;
    if (wid >= N) return;
    int n = wid;
    float ad = ad2[n];
    int beg = rowptr[n], end = rowptr[n + 1];
    float acc = 0.f, den = 0.f;
    for (int i = beg; i < end; ++i) {
        int src = esrc[i];
        float w = __expf(lrelu_f(as2[src] + ad));
        den += w;
        acc += w * h2[(size_t)src * 64 + lane];
    }
    float inv = 1.f / (den + 1e-16f);
    const float* S2 = par + 512;
    const float* C2 = par + 576;
    outb[(size_t)n * 64 + lane] = elu_f(acc * inv * S2[lane] + C2[lane]);
}

// ---------------- launch ----------------
extern "C" void kernel_launch(void* const* d_in, const int* in_sizes, int n_in,
                              void* d_out, int out_size, void* d_ws, size_t ws_size,
                              hipStream_t stream)
{
    const float* x      = (const float*)d_in[0];
    const void*  ei     = d_in[1];
    const float* W1     = (const float*)d_in[2];
    const float* a_src1 = (const float*)d_in[3];
    const float* a_dst1 = (const float*)d_in[4];
    const float* b1     = (const float*)d_in[5];
    const float* W2     = (const float*)d_in[6];
    const float* a_src2 = (const float*)d_in[7];
    const float* a_dst2 = (const float*)d_in[8];
    const float* b2     = (const float*)d_in[9];
    const float* Wp     = (const float*)d_in[10];
    const float* bp     = (const float*)d_in[11];
    const float* g1 = (const float*)d_in[12], *be1 = (const float*)d_in[13];
    const float* m1 = (const float*)d_in[14], *v1  = (const float*)d_in[15];
    const float* g2 = (const float*)d_in[16], *be2 = (const float*)d_in[17];
    const float* m2 = (const float*)d_in[18], *v2  = (const float*)d_in[19];
    const float* g3 = (const float*)d_in[20], *be3 = (const float*)d_in[21];
    const float* m3 = (const float*)d_in[22], *v3  = (const float*)d_in[23];
    float* out = (float*)d_out;

    const int N  = in_sizes[0] / 128;
    const int E  = in_sizes[1] / 2;
    const int ET = E + N;

    // workspace layout (float units, 16-float aligned)
    auto al = [](size_t v) { return (v + 15) & ~(size_t)15; };
    float* ws = (float*)d_ws;
    size_t o_par     = 0;                       // 1024
    size_t o_flag    = 1024;                    // 16 (int flag)
    size_t o_rowptr  = 1040;
    size_t o_fillptr = al(o_rowptr + N + 1);
    size_t o_esrc    = al(o_fillptr + N + 1);
    size_t o_as1     = al(o_esrc + ET);
    size_t o_ad1     = al(o_as1 + (size_t)N * 8);
    size_t o_as2     = al(o_ad1 + (size_t)N * 8);
    size_t o_ad2     = al(o_as2 + N);
    size_t o_h1      = al(o_ad2 + N);
    size_t o_h1b     = al(o_h1 + (size_t)N * 256);
    size_t o_h2      = al(o_h1b + (size_t)N * 256);
    size_t o_g2      = o_h1;                    // reuse: h1 dead after agg1

    float* par     = ws + o_par;
    int*   flag64  = (int*)(ws + o_flag);
    int*   rowptr  = (int*)(ws + o_rowptr);
    int*   fillptr = (int*)(ws + o_fillptr);
    int*   esrc    = (int*)(ws + o_esrc);
    float* as1     = ws + o_as1;
    float* ad1     = ws + o_ad1;
    float* as2     = ws + o_as2;
    float* ad2     = ws + o_ad2;
    float* h1      = ws + o_h1;
    float* h1b     = ws + o_h1b;
    float* h2      = ws + o_h2;
    float* g2buf   = ws + o_g2;

    // 0) dtype detect + param fold + zero degree counters
    detect_dtype_kernel<<<1, 256, 0, stream>>>(ei, min(2 * E, 4096), (long long)N, flag64);
    precompute_kernel<<<1, 256, 0, stream>>>(b1, b2, bp, g1, be1, m1, v1,
                                             g2, be2, m2, v2, g3, be3, m3, v3, par);
    hipMemsetAsync(fillptr, 0, (N + 1) * sizeof(int), stream);

    // 1) CSR by dst
    int ebl = (ET + 255) / 256;
    count_kernel<<<ebl, 256, 0, stream>>>(ei, E, N, flag64, fillptr);
    scan_kernel<<<1, 1024, 0, stream>>>(fillptr, rowptr, N);
    fill_kernel<<<ebl, 256, 0, stream>>>(ei, E, N, flag64, fillptr, esrc);

    // 2) layer 1
    int mb = (N + 63) / 64;
    gemm64_kernel<<<dim3(mb, 4), 256, 0, stream>>>(x, W1, h1, N, 128, 256, nullptr, nullptr);
    att1_kernel<<<N, 256, 0, stream>>>(h1, a_src1, a_dst1, as1, ad1, N);
    int abl = ((size_t)N * 64 + 255) / 256;
    agg1_kernel<<<abl, 256, 0, stream>>>(h1, as1, ad1, rowptr, esrc, par, h1b, N);

    // 3) layer 2
    gemm64_kernel<<<dim3(mb, 1), 256, 0, stream>>>(h1b, W2, h2, N, 256, 64, nullptr, nullptr);
    att2_kernel<<<(N * 64 + 255) / 256, 256, 0, stream>>>(h2, a_src2, a_dst2, as2, ad2, N);
    agg2_kernel<<<abl, 256, 0, stream>>>(h2, as2, ad2, rowptr, esrc, par, g2buf, N);

    // 4) projection + BN3 (folded)
    gemm64_kernel<<<dim3(mb, 2), 256, 0, stream>>>(g2buf, Wp, out, N, 64, 128,
                                                   par + 640, par + 768);
}

// Round 2
// 462.393 us; speedup vs baseline: 1.3561x; 1.3561x over previous
//
#include <hip/hip_runtime.h>
#include <math.h>

#define NEG_SLOPE 0.2f
#define BN_EPS 1e-5f

typedef __bf16 bf16x8 __attribute__((ext_vector_type(8)));
typedef float  f32x4  __attribute__((ext_vector_type(4)));

__device__ __forceinline__ float elu_f(float x){ return x > 0.f ? x : expm1f(x); }
__device__ __forceinline__ float lrelu_f(float x){ return x > 0.f ? x : NEG_SLOPE * x; }

__device__ __forceinline__ float b2f(ushort u){
    union { uint i; float f; } v; v.i = (uint)u << 16; return v.f;
}
__device__ __forceinline__ ushort f2b(float f){
    union { float f; uint i; } v; v.f = f;
    uint r = v.i + 0x7FFFu + ((v.i >> 16) & 1u);   // RTN-even
    return (ushort)(r >> 16);
}

// ---------------- dtype detect (int64 vs int32 edge_index) ----------------
__global__ void detect_dtype_kernel(const void* ei, int n_check, long long N, int* flag64)
{
    __shared__ int ok_s;
    int t = threadIdx.x;
    if (t == 0) ok_s = 1;
    __syncthreads();
    const long long* p = (const long long*)ei;
    for (int i = t; i < n_check; i += blockDim.x) {
        long long v = p[i];
        if (v < 0 || v >= N) ok_s = 0;
    }
    __syncthreads();
    if (t == 0) *flag64 = ok_s;
}

__device__ __forceinline__ void get_edge(const void* ei, int e, int E, int f64, int& s, int& d)
{
    if (e < E) {
        if (f64) { const long long* p = (const long long*)ei; s = (int)p[e]; d = (int)p[E + e]; }
        else     { const int*       p = (const int*)ei;       s = p[e];      d = p[E + e]; }
    } else {
        s = d = e - E;
    }
}

// ---------------- CSR build ----------------
__global__ void count_kernel(const void* ei, int E, int N, const int* flag64, int* deg)
{
    int i = blockIdx.x * blockDim.x + threadIdx.x;
    int ET = E + N;
    if (i >= ET) return;
    int s, d;
    get_edge(ei, i, E, *flag64, s, d);
    atomicAdd(&deg[d], 1);
}

__global__ void scan_kernel(int* deg_fill, int* rowptr, int N)
{
    __shared__ int sums[1024];
    __shared__ int offs[1024];
    int t = threadIdx.x;
    int chunk = (N + 1023) / 1024;
    int b = t * chunk;
    int e = min(N, b + chunk);
    int s = 0;
    for (int i = b; i < e; ++i) s += deg_fill[i];
    sums[t] = s;
    __syncthreads();
    if (t == 0) { int r = 0; for (int i = 0; i < 1024; ++i) { offs[i] = r; r += sums[i]; } }
    __syncthreads();
    int pref = offs[t];
    for (int i = b; i < e; ++i) {
        int d = deg_fill[i];
        rowptr[i] = pref;
        deg_fill[i] = pref;
        pref += d;
    }
    if (t == 1023) rowptr[N] = pref;
}

__global__ void fill_kernel(const void* ei, int E, int N, const int* flag64,
                            int* fillptr, int* esrc)
{
    int i = blockIdx.x * blockDim.x + threadIdx.x;
    int ET = E + N;
    if (i >= ET) return;
    int s, d;
    get_edge(ei, i, E, *flag64, s, d);
    int pos = atomicAdd(&fillptr[d], 1);
    esrc[pos] = s;
}

// ---------------- BN fold precompute (+ mfma_ok init) ----------------
__global__ void precompute_kernel(const float* b1, const float* b2, const float* bp,
    const float* g1, const float* be1, const float* m1, const float* v1,
    const float* g2, const float* be2, const float* m2, const float* v2,
    const float* g3, const float* be3, const float* m3, const float* v3,
    float* par, int* mfma_ok)
{
    int t = threadIdx.x;
    if (t == 0) *mfma_ok = 1;
    if (t < 256) { float s = g1[t] * rsqrtf(v1[t] + BN_EPS); par[t] = s;        par[256 + t] = b1[t] * s + be1[t] - m1[t] * s; }
    if (t < 64)  { float s = g2[t] * rsqrtf(v2[t] + BN_EPS); par[512 + t] = s;  par[576 + t] = b2[t] * s + be2[t] - m2[t] * s; }
    if (t < 128) { float s = g3[t] * rsqrtf(v3[t] + BN_EPS); par[640 + t] = s;  par[768 + t] = bp[t] * s + be3[t] - m3[t] * s; }
}

// ---------------- weight transpose + convert: dst[n*K+k] = src[k*N+n] ----------------
__global__ void transpose_bf16(const float* __restrict__ src, ushort* __restrict__ dst, int K, int N)
{
    int idx = blockIdx.x * blockDim.x + threadIdx.x;
    if (idx >= K * N) return;
    int n = idx / K, k = idx - n * K;
    dst[idx] = f2b(src[k * N + n]);
}

// ---------------- MFMA bf16 GEMM: C[M,NC] = A[M,K] @ Bt[NC,K]^T ----------------
// ATYPE: 0 = A fp32 (convert inline), 1 = A bf16(ushort)
// OMODE: 0 = store bf16, 1 = store fp32 with per-col y = acc*S + C
template<int ATYPE, int OMODE>
__global__ __launch_bounds__(256) void mgemm_kernel(const void* __restrict__ Ap,
    const ushort* __restrict__ Bt, void* __restrict__ Cp, int M, int K, int NC,
    const float* __restrict__ S, const float* __restrict__ Cc)
{
    const int BM = 128, BN = 64, BK = 64, LDA = 72;
    __shared__ __align__(16) ushort As[BM][LDA];
    __shared__ __align__(16) ushort Bs[BN][LDA];
    int t = threadIdx.x;
    int m0 = blockIdx.x * BM, n0 = blockIdx.y * BN;
    int w = t >> 6, l = t & 63;
    int wm = w >> 1, wn = w & 1;
    int r16 = l & 15, kg = l >> 4;

    f32x4 acc[4][2];
    #pragma unroll
    for (int mi = 0; mi < 4; ++mi)
        #pragma unroll
        for (int ni = 0; ni < 2; ++ni)
            acc[mi][ni] = (f32x4){0.f, 0.f, 0.f, 0.f};

    for (int kb = 0; kb < K; kb += BK) {
        if (ATYPE == 0) {
            const float* A = (const float*)Ap;
            #pragma unroll
            for (int p = 0; p < 8; ++p) {
                int r = (t >> 4) + p * 16, c4 = (t & 15) * 4;
                int gm = m0 + r;
                float4 v = (gm < M) ? *reinterpret_cast<const float4*>(&A[(size_t)gm * K + kb + c4])
                                    : make_float4(0.f, 0.f, 0.f, 0.f);
                ushort4 u; u.x = f2b(v.x); u.y = f2b(v.y); u.z = f2b(v.z); u.w = f2b(v.w);
                *reinterpret_cast<ushort4*>(&As[r][c4]) = u;
            }
        } else {
            const ushort* A = (const ushort*)Ap;
            #pragma unroll
            for (int p = 0; p < 4; ++p) {
                int r = (t >> 3) + p * 32, c8 = (t & 7) * 8;
                int gm = m0 + r;
                uint4 v = (gm < M) ? *reinterpret_cast<const uint4*>(&A[(size_t)gm * K + kb + c8])
                                   : make_uint4(0u, 0u, 0u, 0u);
                *reinterpret_cast<uint4*>(&As[r][c8]) = v;
            }
        }
        #pragma unroll
        for (int p = 0; p < 2; ++p) {
            int r = (t >> 3) + p * 32, c8 = (t & 7) * 8;
            uint4 v = *reinterpret_cast<const uint4*>(&Bt[(size_t)(n0 + r) * K + kb + c8]);
            *reinterpret_cast<uint4*>(&Bs[r][c8]) = v;
        }
        __syncthreads();
        #pragma unroll
        for (int kk = 0; kk < 2; ++kk) {
            bf16x8 bB[2], bA[4];
            #pragma unroll
            for (int ni = 0; ni < 2; ++ni)
                bB[ni] = *reinterpret_cast<const bf16x8*>(&Bs[wn * 32 + ni * 16 + r16][kk * 32 + kg * 8]);
            #pragma unroll
            for (int mi = 0; mi < 4; ++mi)
                bA[mi] = *reinterpret_cast<const bf16x8*>(&As[wm * 64 + mi * 16 + r16][kk * 32 + kg * 8]);
            #pragma unroll
            for (int mi = 0; mi < 4; ++mi)
                #pragma unroll
                for (int ni = 0; ni < 2; ++ni)
                    acc[mi][ni] = __builtin_amdgcn_mfma_f32_16x16x32_bf16(bA[mi], bB[ni], acc[mi][ni], 0, 0, 0);
        }
        __syncthreads();
    }
    #pragma unroll
    for (int mi = 0; mi < 4; ++mi) {
        #pragma unroll
        for (int ni = 0; ni < 2; ++ni) {
            #pragma unroll
            for (int rg = 0; rg < 4; ++rg) {
                int gm = m0 + wm * 64 + mi * 16 + kg * 4 + rg;
                int gc = n0 + wn * 32 + ni * 16 + r16;
                if (gm < M) {
                    float v = acc[mi][ni][rg];
                    if (OMODE == 0) ((ushort*)Cp)[(size_t)gm * NC + gc] = f2b(v);
                    else            ((float*)Cp)[(size_t)gm * NC + gc] = v * S[gc] + Cc[gc];
                }
            }
        }
    }
}

// ---------------- MFMA layout self-check (sets *ok=0 on mismatch) ----------------
__global__ void check_kernel(const float* __restrict__ x, const float* __restrict__ W1,
                             const ushort* __restrict__ h1, int M, int* ok)
{
    int t = threadIdx.x;   // 256 cols
    int rows[3]; rows[0] = 0; rows[1] = 65; rows[2] = M - 1;
    bool bad = false;
    for (int rr = 0; rr < 3; ++rr) {
        int r = rows[rr];
        float ref = 0.f;
        for (int k = 0; k < 128; ++k) ref += x[(size_t)r * 128 + k] * W1[k * 256 + t];
        float got = b2f(h1[(size_t)r * 256 + t]);
        if (!(fabsf(got - ref) <= 0.06f)) bad = true;   // NaN-safe
    }
    if (bad) *ok = 0;
}

// ---------------- fp32 fallback GEMM (early-exits when MFMA verified ok) ----------------
template<int ATYPE, int OMODE>
__global__ void gemm64_kernel(const void* __restrict__ Ap, const float* __restrict__ B,
                              void* __restrict__ Cp, int M, int K, int NC,
                              const float* __restrict__ S, const float* __restrict__ Cc,
                              const int* __restrict__ ok)
{
    if (*ok) return;
    const int BM = 64, BN = 64, BK = 32;
    __shared__ float Asl[BK][BM + 1];
    __shared__ __align__(16) float Bsl[BK][BN];
    int tx = threadIdx.x & 15, ty = threadIdx.x >> 4;
    int m0 = blockIdx.x * BM, n0 = blockIdx.y * BN;
    float acc[4][4] = {};

    for (int k0 = 0; k0 < K; k0 += BK) {
        #pragma unroll
        for (int p = 0; p < (BM * BK) / 256; ++p) {
            int idx = threadIdx.x + p * 256;
            int m = idx >> 5, k = idx & 31;
            int gm = m0 + m;
            float v = 0.f;
            if (gm < M) {
                if (ATYPE == 0) v = ((const float*)Ap)[(size_t)gm * K + k0 + k];
                else            v = b2f(((const ushort*)Ap)[(size_t)gm * K + k0 + k]);
            }
            Asl[k][m] = v;
        }
        #pragma unroll
        for (int p = 0; p < (BK * BN) / 256; ++p) {
            int idx = threadIdx.x + p * 256;
            int k = idx >> 6, n = idx & 63;
            Bsl[k][n] = B[(size_t)(k0 + k) * NC + n0 + n];
        }
        __syncthreads();
        #pragma unroll
        for (int kk = 0; kk < BK; ++kk) {
            float4 b = *reinterpret_cast<const float4*>(&Bsl[kk][tx * 4]);
            float a[4];
            #pragma unroll
            for (int i = 0; i < 4; ++i) a[i] = Asl[kk][ty * 4 + i];
            #pragma unroll
            for (int i = 0; i < 4; ++i) {
                acc[i][0] += a[i] * b.x;
                acc[i][1] += a[i] * b.y;
                acc[i][2] += a[i] * b.z;
                acc[i][3] += a[i] * b.w;
            }
        }
        __syncthreads();
    }
    #pragma unroll
    for (int i = 0; i < 4; ++i) {
        int gm = m0 + ty * 4 + i;
        if (gm >= M) continue;
        int gc = n0 + tx * 4;
        #pragma unroll
        for (int j = 0; j < 4; ++j) {
            float v = acc[i][j];
            if (OMODE == 0) ((ushort*)Cp)[(size_t)gm * NC + gc + j] = f2b(v);
            else            ((float*)Cp)[(size_t)gm * NC + gc + j] = v * S[gc + j] + Cc[gc + j];
        }
    }
}

// ---------------- attention coefficients layer 1 (bf16 h1) ----------------
__global__ void att1_kernel(const ushort* __restrict__ h1,
                            const float* __restrict__ a_src, const float* __restrict__ a_dst,
                            float* __restrict__ as1, float* __restrict__ ad1, int N)
{
    int wid = (blockIdx.x * blockDim.x + threadIdx.x) >> 6;
    int lane = threadIdx.x & 63;
    if (wid >= N) return;
    ushort4 hv = *reinterpret_cast<const ushort4*>(&h1[(size_t)wid * 256 + lane * 4]);
    int f0 = lane * 4;
    float vx = b2f(hv.x), vy = b2f(hv.y), vz = b2f(hv.z), vw = b2f(hv.w);
    float s = vx * a_src[f0] + vy * a_src[f0 + 1] + vz * a_src[f0 + 2] + vw * a_src[f0 + 3];
    float d = vx * a_dst[f0] + vy * a_dst[f0 + 1] + vz * a_dst[f0 + 2] + vw * a_dst[f0 + 3];
    s += __shfl_xor(s, 1); s += __shfl_xor(s, 2); s += __shfl_xor(s, 4);
    d += __shfl_xor(d, 1); d += __shfl_xor(d, 2); d += __shfl_xor(d, 4);
    if ((lane & 7) == 0) {
        as1[wid * 8 + (lane >> 3)] = s;
        ad1[wid * 8 + (lane >> 3)] = d;
    }
}

// ---------------- attention coefficients layer 2 (bf16 h2) ----------------
__global__ void att2_kernel(const ushort* __restrict__ h2,
                            const float* __restrict__ a_src, const float* __restrict__ a_dst,
                            float* __restrict__ as2, float* __restrict__ ad2, int N)
{
    int wid = (blockIdx.x * blockDim.x + threadIdx.x) >> 6;
    int lane = threadIdx.x & 63;
    if (wid >= N) return;
    float v = b2f(h2[(size_t)wid * 64 + lane]);
    float s = v * a_src[lane];
    float d = v * a_dst[lane];
    #pragma unroll
    for (int off = 32; off; off >>= 1) {
        s += __shfl_down(s, off, 64);
        d += __shfl_down(d, off, 64);
    }
    if (lane == 0) { as2[wid] = s; ad2[wid] = d; }
}

// ---------------- aggregation layer 1: wave per node (bf16 gather) ----------------
__global__ void agg1_kernel(const ushort* __restrict__ h1,
                            const float* __restrict__ as1, const float* __restrict__ ad1,
                            const int* __restrict__ rowptr, const int* __restrict__ esrc,
                            const float* __restrict__ par,
                            ushort* __restrict__ outb, int N)
{
    int wid = (blockIdx.x * blockDim.x + threadIdx.x) >> 6;
    int lane = threadIdx.x & 63;
    if (wid >= N) return;
    int n = wid;
    float ad = ad1[n * 8 + (lane & 7)];
    int beg = rowptr[n], end = rowptr[n + 1];
    float4 acc = make_float4(0.f, 0.f, 0.f, 0.f);
    float den = 0.f;
    int hsrc = lane >> 3;   // lane holding this lane's head weight (feats 4l -> head l>>3)
    for (int i = beg; i < end; ++i) {
        int src = esrc[i];
        float as = as1[src * 8 + (lane & 7)];
        float w = __expf(lrelu_f(as + ad));
        den += w;
        float wl = __shfl(w, hsrc, 64);
        ushort4 hv = *reinterpret_cast<const ushort4*>(&h1[(size_t)src * 256 + lane * 4]);
        acc.x += wl * b2f(hv.x);
        acc.y += wl * b2f(hv.y);
        acc.z += wl * b2f(hv.z);
        acc.w += wl * b2f(hv.w);
    }
    float dh = __shfl(den, hsrc, 64);
    float inv = 1.f / (dh + 1e-16f);
    int f0 = lane * 4;
    const float* S1 = par;
    const float* C1 = par + 256;
    ushort4 o;
    o.x = f2b(elu_f(acc.x * inv * S1[f0 + 0] + C1[f0 + 0]));
    o.y = f2b(elu_f(acc.y * inv * S1[f0 + 1] + C1[f0 + 1]));
    o.z = f2b(elu_f(acc.z * inv * S1[f0 + 2] + C1[f0 + 2]));
    o.w = f2b(elu_f(acc.w * inv * S1[f0 + 3] + C1[f0 + 3]));
    *reinterpret_cast<ushort4*>(&outb[(size_t)n * 256 + f0]) = o;
}

// ---------------- aggregation layer 2: wave per node, 2 edges/iter (half-waves) ----------------
__global__ void agg2_kernel(const ushort* __restrict__ h2,
                            const float* __restrict__ as2, const float* __restrict__ ad2,
                            const int* __restrict__ rowptr, const int* __restrict__ esrc,
                            const float* __restrict__ par,
                            ushort* __restrict__ outb, int N)
{
    int wid = (blockIdx.x * blockDim.x + threadIdx.x) >> 6;
    int lane = threadIdx.x & 63;
    if (wid >= N) return;
    int li = lane & 31, half = lane >> 5;
    int n = wid;
    float ad = ad2[n];
    int beg = rowptr[n], end = rowptr[n + 1];
    float a0 = 0.f, a1 = 0.f, den = 0.f;
    for (int i = beg + half; i < end; i += 2) {
        int src = esrc[i];
        float w = __expf(lrelu_f(as2[src] + ad));
        den += w;
        uint hv = *reinterpret_cast<const uint*>(&h2[(size_t)src * 64 + li * 2]);
        a0 += w * b2f((ushort)(hv & 0xffffu));
        a1 += w * b2f((ushort)(hv >> 16));
    }
    a0  += __shfl_xor(a0, 32);
    a1  += __shfl_xor(a1, 32);
    den += __shfl_xor(den, 32);
    float inv = 1.f / (den + 1e-16f);
    if (half == 0) {
        int f = li * 2;
        const float* S2 = par + 512;
        const float* C2 = par + 576;
        ushort2 o;
        o.x = f2b(elu_f(a0 * inv * S2[f] + C2[f]));
        o.y = f2b(elu_f(a1 * inv * S2[f + 1] + C2[f + 1]));
        *reinterpret_cast<ushort2*>(&outb[(size_t)n * 64 + f]) = o;
    }
}

// ---------------- launch ----------------
extern "C" void kernel_launch(void* const* d_in, const int* in_sizes, int n_in,
                              void* d_out, int out_size, void* d_ws, size_t ws_size,
                              hipStream_t stream)
{
    const float* x      = (const float*)d_in[0];
    const void*  ei     = d_in[1];
    const float* W1     = (const float*)d_in[2];
    const float* a_src1 = (const float*)d_in[3];
    const float* a_dst1 = (const float*)d_in[4];
    const float* b1     = (const float*)d_in[5];
    const float* W2     = (const float*)d_in[6];
    const float* a_src2 = (const float*)d_in[7];
    const float* a_dst2 = (const float*)d_in[8];
    const float* b2     = (const float*)d_in[9];
    const float* Wp     = (const float*)d_in[10];
    const float* bp     = (const float*)d_in[11];
    const float* g1 = (const float*)d_in[12], *be1 = (const float*)d_in[13];
    const float* m1 = (const float*)d_in[14], *v1  = (const float*)d_in[15];
    const float* g2 = (const float*)d_in[16], *be2 = (const float*)d_in[17];
    const float* m2 = (const float*)d_in[18], *v2  = (const float*)d_in[19];
    const float* g3 = (const float*)d_in[20], *be3 = (const float*)d_in[21];
    const float* m3 = (const float*)d_in[22], *v3  = (const float*)d_in[23];
    float* out = (float*)d_out;

    const int N  = in_sizes[0] / 128;
    const int E  = in_sizes[1] / 2;
    const int ET = E + N;

    // byte-addressed workspace layout, 256B-aligned chunks
    char* base = (char*)d_ws;
    size_t off = 0;
    auto alloc = [&](size_t bytes) -> char* {
        char* p = base + off;
        off += (bytes + 255) & ~(size_t)255;
        return p;
    };
    float*  par     = (float*)alloc(1024 * 4);
    int*    flag64  = (int*)alloc(256);
    int*    mfma_ok = (int*)alloc(256);
    int*    rowptr  = (int*)alloc((size_t)(N + 1) * 4);
    int*    fillptr = (int*)alloc((size_t)(N + 1) * 4);
    int*    esrc    = (int*)alloc((size_t)ET * 4);
    float*  as1     = (float*)alloc((size_t)N * 8 * 4);
    float*  ad1     = (float*)alloc((size_t)N * 8 * 4);
    float*  as2     = (float*)alloc((size_t)N * 4);
    float*  ad2     = (float*)alloc((size_t)N * 4);
    ushort* wt1     = (ushort*)alloc(256 * 128 * 2);
    ushort* wt2     = (ushort*)alloc(64 * 256 * 2);
    ushort* wtp     = (ushort*)alloc(128 * 64 * 2);
    ushort* h1      = (ushort*)alloc((size_t)N * 256 * 2);
    ushort* h1b     = (ushort*)alloc((size_t)N * 256 * 2);
    ushort* h2      = (ushort*)alloc((size_t)N * 64 * 2);
    ushort* g2buf   = (ushort*)alloc((size_t)N * 64 * 2);

    // 0) setup
    detect_dtype_kernel<<<1, 256, 0, stream>>>(ei, min(2 * E, 4096), (long long)N, flag64);
    precompute_kernel<<<1, 256, 0, stream>>>(b1, b2, bp, g1, be1, m1, v1,
                                             g2, be2, m2, v2, g3, be3, m3, v3, par, mfma_ok);
    transpose_bf16<<<(128 * 256 + 255) / 256, 256, 0, stream>>>(W1, wt1, 128, 256);
    transpose_bf16<<<(256 * 64 + 255) / 256, 256, 0, stream>>>(W2, wt2, 256, 64);
    transpose_bf16<<<(64 * 128 + 255) / 256, 256, 0, stream>>>(Wp, wtp, 64, 128);
    hipMemsetAsync(fillptr, 0, (N + 1) * sizeof(int), stream);

    // 1) CSR by dst
    int ebl = (ET + 255) / 256;
    count_kernel<<<ebl, 256, 0, stream>>>(ei, E, N, flag64, fillptr);
    scan_kernel<<<1, 1024, 0, stream>>>(fillptr, rowptr, N);
    fill_kernel<<<ebl, 256, 0, stream>>>(ei, E, N, flag64, fillptr, esrc);

    // 2) layer 1: GEMM (MFMA + checked fallback), attention, aggregation
    int mb128 = (N + 127) / 128;
    int mb64  = (N + 63) / 64;
    mgemm_kernel<0, 0><<<dim3(mb128, 4), 256, 0, stream>>>(x, wt1, h1, N, 128, 256, nullptr, nullptr);
    check_kernel<<<1, 256, 0, stream>>>(x, W1, h1, N, mfma_ok);
    gemm64_kernel<0, 0><<<dim3(mb64, 4), 256, 0, stream>>>(x, W1, h1, N, 128, 256, nullptr, nullptr, mfma_ok);

    int wbl = (N + 3) / 4;   // wave-per-node kernels: N*64 threads / 256
    att1_kernel<<<wbl, 256, 0, stream>>>(h1, a_src1, a_dst1, as1, ad1, N);
    agg1_kernel<<<wbl, 256, 0, stream>>>(h1, as1, ad1, rowptr, esrc, par, h1b, N);

    // 3) layer 2
    mgemm_kernel<1, 0><<<dim3(mb128, 1), 256, 0, stream>>>(h1b, wt2, h2, N, 256, 64, nullptr, nullptr);
    gemm64_kernel<1, 0><<<dim3(mb64, 1), 256, 0, stream>>>(h1b, W2, h2, N, 256, 64, nullptr, nullptr, mfma_ok);
    att2_kernel<<<wbl, 256, 0, stream>>>(h2, a_src2, a_dst2, as2, ad2, N);
    agg2_kernel<<<wbl, 256, 0, stream>>>(h2, as2, ad2, rowptr, esrc, par, g2buf, N);

    // 4) projection + BN3 folded
    mgemm_kernel<1, 1><<<dim3(mb128, 2), 256, 0, stream>>>(g2buf, wtp, out, N, 64, 128, par + 640, par + 768);
    gemm64_kernel<1, 1><<<dim3(mb64, 2), 256, 0, stream>>>(g2buf, Wp, out, N, 64, 128, par + 640, par + 768, mfma_ok);
}

// Round 3
// 364.578 us; speedup vs baseline: 1.7200x; 1.2683x over previous
//
#include <hip/hip_runtime.h>
#include <math.h>

#define NEG_SLOPE 0.2f
#define BN_EPS 1e-5f

typedef __bf16 bf16x8 __attribute__((ext_vector_type(8)));
typedef float  f32x4  __attribute__((ext_vector_type(4)));

__device__ __forceinline__ float elu_f(float x){ return x > 0.f ? x : expm1f(x); }
__device__ __forceinline__ float lrelu_f(float x){ return x > 0.f ? x : NEG_SLOPE * x; }

__device__ __forceinline__ float b2f(ushort u){
    union { uint i; float f; } v; v.i = (uint)u << 16; return v.f;
}
__device__ __forceinline__ ushort f2b(float f){
    union { float f; uint i; } v; v.f = f;
    uint r = v.i + 0x7FFFu + ((v.i >> 16) & 1u);   // RTN-even
    return (ushort)(r >> 16);
}

// ---------------- dtype detect (int64 vs int32 edge_index) ----------------
__global__ void detect_dtype_kernel(const void* ei, int n_check, long long N, int* flag64)
{
    __shared__ int ok_s;
    int t = threadIdx.x;
    if (t == 0) ok_s = 1;
    __syncthreads();
    const long long* p = (const long long*)ei;
    for (int i = t; i < n_check; i += blockDim.x) {
        long long v = p[i];
        if (v < 0 || v >= N) ok_s = 0;
    }
    __syncthreads();
    if (t == 0) *flag64 = ok_s;
}

__device__ __forceinline__ void get_edge(const void* ei, int e, int E, int f64, int& s, int& d)
{
    if (e < E) {
        if (f64) { const long long* p = (const long long*)ei; s = (int)p[e]; d = (int)p[E + e]; }
        else     { const int*       p = (const int*)ei;       s = p[e];      d = p[E + e]; }
    } else {
        s = d = e - E;
    }
}

// ---------------- CSR build ----------------
__global__ void count_kernel(const void* ei, int E, int N, const int* flag64, int* deg)
{
    int i = blockIdx.x * blockDim.x + threadIdx.x;
    int ET = E + N;
    if (i >= ET) return;
    int s, d;
    get_edge(ei, i, E, *flag64, s, d);
    atomicAdd(&deg[d], 1);
}

// hierarchical scan: 13 blocks x 4096 elems
__global__ void scan1_kernel(const int* __restrict__ deg, int N, int* __restrict__ bsum)
{
    int b = blockIdx.x, t = threadIdx.x;
    int base = b * 4096 + t * 16;
    int s = 0;
    #pragma unroll
    for (int k = 0; k < 16; k += 4) {
        int idx = base + k;
        if (idx + 3 < N) {
            int4 v = *reinterpret_cast<const int4*>(&deg[idx]);
            s += v.x + v.y + v.z + v.w;
        } else {
            for (int q = 0; q < 4; ++q) if (idx + q < N) s += deg[idx + q];
        }
    }
    #pragma unroll
    for (int off = 1; off < 64; off <<= 1) s += __shfl_xor(s, off);
    __shared__ int wsum[4];
    if ((t & 63) == 0) wsum[t >> 6] = s;
    __syncthreads();
    if (t == 0) bsum[b] = wsum[0] + wsum[1] + wsum[2] + wsum[3];
}

__global__ void scan2_kernel(const int* __restrict__ bsum, int nb, int* __restrict__ bpre)
{
    if (threadIdx.x == 0) {
        int r = 0;
        for (int i = 0; i < nb; ++i) { bpre[i] = r; r += bsum[i]; }
        bpre[nb] = r;
    }
}

__global__ void scan3_kernel(const int* __restrict__ deg, int N,
                             const int* __restrict__ bpre, int nb,
                             int* __restrict__ rowptr, int* __restrict__ fillptr)
{
    int b = blockIdx.x, t = threadIdx.x;
    int base = b * 4096 + t * 16;
    int loc[16];
    int s = 0;
    #pragma unroll
    for (int k = 0; k < 16; ++k) {
        int idx = base + k;
        int d = (idx < N) ? deg[idx] : 0;
        loc[k] = s; s += d;
    }
    int lane = t & 63;
    int incl = s;
    #pragma unroll
    for (int off = 1; off < 64; off <<= 1) {
        int v = __shfl_up(incl, off);
        if (lane >= off) incl += v;
    }
    __shared__ int wsum[4];
    if (lane == 63) wsum[t >> 6] = incl;
    __syncthreads();
    int woff = 0;
    int w = t >> 6;
    for (int i = 0; i < w; ++i) woff += wsum[i];
    int off0 = bpre[b] + woff + incl - s;     // exclusive prefix for this thread
    #pragma unroll
    for (int k = 0; k < 16; ++k) {
        int idx = base + k;
        if (idx < N) { rowptr[idx] = off0 + loc[k]; fillptr[idx] = off0 + loc[k]; }
    }
    if (b == 0 && t == 0) rowptr[N] = bpre[nb];
}

__global__ void fill_kernel(const void* ei, int E, int N, const int* flag64,
                            int* fillptr, int* esrc)
{
    int i = blockIdx.x * blockDim.x + threadIdx.x;
    int ET = E + N;
    if (i >= ET) return;
    int s, d;
    get_edge(ei, i, E, *flag64, s, d);
    int pos = atomicAdd(&fillptr[d], 1);
    esrc[pos] = s;
}

// ---------------- BN fold precompute (+ mfma_ok init) ----------------
__global__ void precompute_kernel(const float* b1, const float* b2, const float* bp,
    const float* g1, const float* be1, const float* m1, const float* v1,
    const float* g2, const float* be2, const float* m2, const float* v2,
    const float* g3, const float* be3, const float* m3, const float* v3,
    float* par, int* mfma_ok)
{
    int t = threadIdx.x;
    if (t == 0) *mfma_ok = 1;
    if (t < 256) { float s = g1[t] * rsqrtf(v1[t] + BN_EPS); par[t] = s;        par[256 + t] = b1[t] * s + be1[t] - m1[t] * s; }
    if (t < 64)  { float s = g2[t] * rsqrtf(v2[t] + BN_EPS); par[512 + t] = s;  par[576 + t] = b2[t] * s + be2[t] - m2[t] * s; }
    if (t < 128) { float s = g3[t] * rsqrtf(v3[t] + BN_EPS); par[640 + t] = s;  par[768 + t] = bp[t] * s + be3[t] - m3[t] * s; }
}

// ---------------- fused weight transpose + bf16 convert ----------------
__global__ void transpose_all_kernel(const float* __restrict__ W1, const float* __restrict__ W2,
                                     const float* __restrict__ Wp,
                                     ushort* __restrict__ wt1, ushort* __restrict__ wt2,
                                     ushort* __restrict__ wtp)
{
    int idx = blockIdx.x * blockDim.x + threadIdx.x;
    if (idx < 32768) {                       // W1: [128,256] -> wt1[n*128+k]
        int n = idx >> 7, k = idx & 127;
        wt1[idx] = f2b(W1[k * 256 + n]);
    } else if (idx < 49152) {                // W2: [256,64] -> wt2[n*256+k]
        int j = idx - 32768;
        int n = j >> 8, k = j & 255;
        wt2[j] = f2b(W2[k * 64 + n]);
    } else if (idx < 57344) {                // Wp: [64,128] -> wtp[n*64+k]
        int j = idx - 49152;
        int n = j >> 6, k = j & 63;
        wtp[j] = f2b(Wp[k * 128 + n]);
    }
}

// ---------------- MFMA bf16 GEMM: C[M,NC] = A[M,K] @ Bt[NC,K]^T ----------------
template<int ATYPE, int OMODE>
__global__ __launch_bounds__(256) void mgemm_kernel(const void* __restrict__ Ap,
    const ushort* __restrict__ Bt, void* __restrict__ Cp, int M, int K, int NC,
    const float* __restrict__ S, const float* __restrict__ Cc)
{
    const int BM = 128, LDA = 72;
    __shared__ __align__(16) ushort As[BM][LDA];
    __shared__ __align__(16) ushort Bs[64][LDA];
    int t = threadIdx.x;
    int m0 = blockIdx.x * BM, n0 = blockIdx.y * 64;
    int w = t >> 6, l = t & 63;
    int wm = w >> 1, wn = w & 1;
    int r16 = l & 15, kg = l >> 4;

    f32x4 acc[4][2];
    #pragma unroll
    for (int mi = 0; mi < 4; ++mi)
        #pragma unroll
        for (int ni = 0; ni < 2; ++ni)
            acc[mi][ni] = (f32x4){0.f, 0.f, 0.f, 0.f};

    for (int kb = 0; kb < K; kb += 64) {
        if (ATYPE == 0) {
            const float* A = (const float*)Ap;
            #pragma unroll
            for (int p = 0; p < 8; ++p) {
                int r = (t >> 4) + p * 16, c4 = (t & 15) * 4;
                int gm = m0 + r;
                float4 v = (gm < M) ? *reinterpret_cast<const float4*>(&A[(size_t)gm * K + kb + c4])
                                    : make_float4(0.f, 0.f, 0.f, 0.f);
                ushort4 u; u.x = f2b(v.x); u.y = f2b(v.y); u.z = f2b(v.z); u.w = f2b(v.w);
                *reinterpret_cast<ushort4*>(&As[r][c4]) = u;
            }
        } else {
            const ushort* A = (const ushort*)Ap;
            #pragma unroll
            for (int p = 0; p < 4; ++p) {
                int r = (t >> 3) + p * 32, c8 = (t & 7) * 8;
                int gm = m0 + r;
                uint4 v = (gm < M) ? *reinterpret_cast<const uint4*>(&A[(size_t)gm * K + kb + c8])
                                   : make_uint4(0u, 0u, 0u, 0u);
                *reinterpret_cast<uint4*>(&As[r][c8]) = v;
            }
        }
        #pragma unroll
        for (int p = 0; p < 2; ++p) {
            int r = (t >> 3) + p * 32, c8 = (t & 7) * 8;
            uint4 v = *reinterpret_cast<const uint4*>(&Bt[(size_t)(n0 + r) * K + kb + c8]);
            *reinterpret_cast<uint4*>(&Bs[r][c8]) = v;
        }
        __syncthreads();
        #pragma unroll
        for (int kk = 0; kk < 2; ++kk) {
            bf16x8 bB[2], bA[4];
            #pragma unroll
            for (int ni = 0; ni < 2; ++ni)
                bB[ni] = *reinterpret_cast<const bf16x8*>(&Bs[wn * 32 + ni * 16 + r16][kk * 32 + kg * 8]);
            #pragma unroll
            for (int mi = 0; mi < 4; ++mi)
                bA[mi] = *reinterpret_cast<const bf16x8*>(&As[wm * 64 + mi * 16 + r16][kk * 32 + kg * 8]);
            #pragma unroll
            for (int mi = 0; mi < 4; ++mi)
                #pragma unroll
                for (int ni = 0; ni < 2; ++ni)
                    acc[mi][ni] = __builtin_amdgcn_mfma_f32_16x16x32_bf16(bA[mi], bB[ni], acc[mi][ni], 0, 0, 0);
        }
        __syncthreads();
    }
    #pragma unroll
    for (int mi = 0; mi < 4; ++mi) {
        #pragma unroll
        for (int ni = 0; ni < 2; ++ni) {
            #pragma unroll
            for (int rg = 0; rg < 4; ++rg) {
                int gm = m0 + wm * 64 + mi * 16 + kg * 4 + rg;
                int gc = n0 + wn * 32 + ni * 16 + r16;
                if (gm < M) {
                    float v = acc[mi][ni][rg];
                    if (OMODE == 0) ((ushort*)Cp)[(size_t)gm * NC + gc] = f2b(v);
                    else            ((float*)Cp)[(size_t)gm * NC + gc] = v * S[gc] + Cc[gc];
                }
            }
        }
    }
}

// ---------------- MFMA layout self-check ----------------
__global__ void check_kernel(const float* __restrict__ x, const float* __restrict__ W1,
                             const ushort* __restrict__ h1, int M, int* ok)
{
    int t = threadIdx.x;
    int rows[3]; rows[0] = 0; rows[1] = 65; rows[2] = M - 1;
    bool bad = false;
    for (int rr = 0; rr < 3; ++rr) {
        int r = rows[rr];
        float ref = 0.f;
        for (int k = 0; k < 128; ++k) ref += x[(size_t)r * 128 + k] * W1[k * 256 + t];
        float got = b2f(h1[(size_t)r * 256 + t]);
        if (!(fabsf(got - ref) <= 0.06f)) bad = true;
    }
    if (bad) *ok = 0;
}

// ---------------- fp32 fallback GEMM (early-exits when MFMA ok) ----------------
template<int ATYPE, int OMODE>
__global__ void gemm64_kernel(const void* __restrict__ Ap, const float* __restrict__ B,
                              void* __restrict__ Cp, int M, int K, int NC,
                              const float* __restrict__ S, const float* __restrict__ Cc,
                              const int* __restrict__ ok)
{
    if (*ok) return;
    const int BM = 64, BN = 64, BK = 32;
    __shared__ float Asl[BK][BM + 1];
    __shared__ __align__(16) float Bsl[BK][BN];
    int tx = threadIdx.x & 15, ty = threadIdx.x >> 4;
    int m0 = blockIdx.x * BM, n0 = blockIdx.y * BN;
    float acc[4][4] = {};

    for (int k0 = 0; k0 < K; k0 += BK) {
        #pragma unroll
        for (int p = 0; p < (BM * BK) / 256; ++p) {
            int idx = threadIdx.x + p * 256;
            int m = idx >> 5, k = idx & 31;
            int gm = m0 + m;
            float v = 0.f;
            if (gm < M) {
                if (ATYPE == 0) v = ((const float*)Ap)[(size_t)gm * K + k0 + k];
                else            v = b2f(((const ushort*)Ap)[(size_t)gm * K + k0 + k]);
            }
            Asl[k][m] = v;
        }
        #pragma unroll
        for (int p = 0; p < (BK * BN) / 256; ++p) {
            int idx = threadIdx.x + p * 256;
            int k = idx >> 6, n = idx & 63;
            Bsl[k][n] = B[(size_t)(k0 + k) * NC + n0 + n];
        }
        __syncthreads();
        #pragma unroll
        for (int kk = 0; kk < BK; ++kk) {
            float4 b = *reinterpret_cast<const float4*>(&Bsl[kk][tx * 4]);
            float a[4];
            #pragma unroll
            for (int i = 0; i < 4; ++i) a[i] = Asl[kk][ty * 4 + i];
            #pragma unroll
            for (int i = 0; i < 4; ++i) {
                acc[i][0] += a[i] * b.x;
                acc[i][1] += a[i] * b.y;
                acc[i][2] += a[i] * b.z;
                acc[i][3] += a[i] * b.w;
            }
        }
        __syncthreads();
    }
    #pragma unroll
    for (int i = 0; i < 4; ++i) {
        int gm = m0 + ty * 4 + i;
        if (gm >= M) continue;
        int gc = n0 + tx * 4;
        #pragma unroll
        for (int j = 0; j < 4; ++j) {
            float v = acc[i][j];
            if (OMODE == 0) ((ushort*)Cp)[(size_t)gm * NC + gc + j] = f2b(v);
            else            ((float*)Cp)[(size_t)gm * NC + gc + j] = v * S[gc + j] + Cc[gc + j];
        }
    }
}

// ---------------- attention coefficients ----------------
__global__ void att1_kernel(const ushort* __restrict__ h1,
                            const float* __restrict__ a_src, const float* __restrict__ a_dst,
                            float* __restrict__ as1, float* __restrict__ ad1, int N)
{
    int wid = (blockIdx.x * blockDim.x + threadIdx.x) >> 6;
    int lane = threadIdx.x & 63;
    if (wid >= N) return;
    ushort4 hv = *reinterpret_cast<const ushort4*>(&h1[(size_t)wid * 256 + lane * 4]);
    int f0 = lane * 4;
    float vx = b2f(hv.x), vy = b2f(hv.y), vz = b2f(hv.z), vw = b2f(hv.w);
    float s = vx * a_src[f0] + vy * a_src[f0 + 1] + vz * a_src[f0 + 2] + vw * a_src[f0 + 3];
    float d = vx * a_dst[f0] + vy * a_dst[f0 + 1] + vz * a_dst[f0 + 2] + vw * a_dst[f0 + 3];
    s += __shfl_xor(s, 1); s += __shfl_xor(s, 2); s += __shfl_xor(s, 4);
    d += __shfl_xor(d, 1); d += __shfl_xor(d, 2); d += __shfl_xor(d, 4);
    if ((lane & 7) == 0) {
        as1[wid * 8 + (lane >> 3)] = s;
        ad1[wid * 8 + (lane >> 3)] = d;
    }
}

__global__ void att2_kernel(const ushort* __restrict__ h2,
                            const float* __restrict__ a_src, const float* __restrict__ a_dst,
                            float* __restrict__ as2, float* __restrict__ ad2, int N)
{
    int wid = (blockIdx.x * blockDim.x + threadIdx.x) >> 6;
    int lane = threadIdx.x & 63;
    if (wid >= N) return;
    float v = b2f(h2[(size_t)wid * 64 + lane]);
    float s = v * a_src[lane];
    float d = v * a_dst[lane];
    #pragma unroll
    for (int off = 32; off; off >>= 1) {
        s += __shfl_down(s, off, 64);
        d += __shfl_down(d, off, 64);
    }
    if (lane == 0) { as2[wid] = s; ad2[wid] = d; }
}

// ---------------- normalized alpha precompute, layer 1 ----------------
// wave per node: lane = (j=sub-edge)<<3 | (h=head); 8 edges x 8 heads per iter
__global__ void wden1_kernel(const float* __restrict__ as1, const float* __restrict__ ad1,
                             const int* __restrict__ rowptr, const int* __restrict__ esrc,
                             float* __restrict__ walpha, int N)
{
    int wid = (blockIdx.x * blockDim.x + threadIdx.x) >> 6;
    int lane = threadIdx.x & 63;
    if (wid >= N) return;
    int h = lane & 7, j = lane >> 3;
    float ad = ad1[wid * 8 + h];
    int beg = rowptr[wid], end = rowptr[wid + 1];
    float den = 0.f;
    for (int i = beg + j; i < end; i += 8) {
        int src = esrc[i];
        float w = __expf(lrelu_f(as1[src * 8 + h] + ad));
        walpha[(size_t)i * 8 + h] = w;
        den += w;
    }
    den += __shfl_xor(den, 8);
    den += __shfl_xor(den, 16);
    den += __shfl_xor(den, 32);
    float inv = 1.f / (den + 1e-16f);
    for (int i = beg + j; i < end; i += 8)
        walpha[(size_t)i * 8 + h] *= inv;
}

// ---------------- normalized alpha precompute, layer 2 ----------------
__global__ void wden2_kernel(const float* __restrict__ as2, const float* __restrict__ ad2,
                             const int* __restrict__ rowptr, const int* __restrict__ esrc,
                             float* __restrict__ walpha, int N)
{
    int wid = (blockIdx.x * blockDim.x + threadIdx.x) >> 6;
    int lane = threadIdx.x & 63;
    if (wid >= N) return;
    float ad = ad2[wid];
    int beg = rowptr[wid], end = rowptr[wid + 1];
    float den = 0.f;
    for (int i = beg + lane; i < end; i += 64) {
        float w = __expf(lrelu_f(as2[esrc[i]] + ad));
        walpha[i] = w;
        den += w;
    }
    #pragma unroll
    for (int off = 1; off < 64; off <<= 1) den += __shfl_xor(den, off);
    float inv = 1.f / (den + 1e-16f);
    for (int i = beg + lane; i < end; i += 64)
        walpha[i] *= inv;
}

// ---------------- aggregation layer 1: wave per node, alpha precomputed ----------------
__global__ void agg1_kernel(const ushort* __restrict__ h1, const float* __restrict__ walpha,
                            const int* __restrict__ rowptr, const int* __restrict__ esrc,
                            const float* __restrict__ par,
                            ushort* __restrict__ outb, int N)
{
    int wid = (blockIdx.x * blockDim.x + threadIdx.x) >> 6;
    int lane = threadIdx.x & 63;
    if (wid >= N) return;
    int hh = lane >> 3;
    int beg = rowptr[wid], end = rowptr[wid + 1];
    float4 acc = make_float4(0.f, 0.f, 0.f, 0.f);
    int i = beg;
    for (; i + 1 < end; i += 2) {
        int s0 = esrc[i], s1 = esrc[i + 1];
        float a0 = walpha[(size_t)i * 8 + hh];
        float a1 = walpha[(size_t)(i + 1) * 8 + hh];
        ushort4 v0 = *reinterpret_cast<const ushort4*>(&h1[(size_t)s0 * 256 + lane * 4]);
        ushort4 v1 = *reinterpret_cast<const ushort4*>(&h1[(size_t)s1 * 256 + lane * 4]);
        acc.x += a0 * b2f(v0.x) + a1 * b2f(v1.x);
        acc.y += a0 * b2f(v0.y) + a1 * b2f(v1.y);
        acc.z += a0 * b2f(v0.z) + a1 * b2f(v1.z);
        acc.w += a0 * b2f(v0.w) + a1 * b2f(v1.w);
    }
    if (i < end) {
        int s0 = esrc[i];
        float a0 = walpha[(size_t)i * 8 + hh];
        ushort4 v0 = *reinterpret_cast<const ushort4*>(&h1[(size_t)s0 * 256 + lane * 4]);
        acc.x += a0 * b2f(v0.x);
        acc.y += a0 * b2f(v0.y);
        acc.z += a0 * b2f(v0.z);
        acc.w += a0 * b2f(v0.w);
    }
    int f0 = lane * 4;
    const float* S1 = par;
    const float* C1 = par + 256;
    ushort4 o;
    o.x = f2b(elu_f(acc.x * S1[f0 + 0] + C1[f0 + 0]));
    o.y = f2b(elu_f(acc.y * S1[f0 + 1] + C1[f0 + 1]));
    o.z = f2b(elu_f(acc.z * S1[f0 + 2] + C1[f0 + 2]));
    o.w = f2b(elu_f(acc.w * S1[f0 + 3] + C1[f0 + 3]));
    *reinterpret_cast<ushort4*>(&outb[(size_t)wid * 256 + f0]) = o;
}

// ---------------- aggregation layer 2: wave per node, half-wave per edge ----------------
__global__ void agg2_kernel(const ushort* __restrict__ h2, const float* __restrict__ walpha,
                            const int* __restrict__ rowptr, const int* __restrict__ esrc,
                            const float* __restrict__ par,
                            ushort* __restrict__ outb, int N)
{
    int wid = (blockIdx.x * blockDim.x + threadIdx.x) >> 6;
    int lane = threadIdx.x & 63;
    if (wid >= N) return;
    int li = lane & 31, half = lane >> 5;
    int beg = rowptr[wid], end = rowptr[wid + 1];
    float a0 = 0.f, a1 = 0.f;
    for (int i = beg + half * 2; i < end; i += 4) {
        {
            int src = esrc[i];
            float w = walpha[i];
            uint hv = *reinterpret_cast<const uint*>(&h2[(size_t)src * 64 + li * 2]);
            a0 += w * b2f((ushort)(hv & 0xffffu));
            a1 += w * b2f((ushort)(hv >> 16));
        }
        if (i + 1 < end) {
            int src = esrc[i + 1];
            float w = walpha[i + 1];
            uint hv = *reinterpret_cast<const uint*>(&h2[(size_t)src * 64 + li * 2]);
            a0 += w * b2f((ushort)(hv & 0xffffu));
            a1 += w * b2f((ushort)(hv >> 16));
        }
    }
    a0 += __shfl_xor(a0, 32);
    a1 += __shfl_xor(a1, 32);
    if (half == 0) {
        int f = li * 2;
        const float* S2 = par + 512;
        const float* C2 = par + 576;
        ushort2 o;
        o.x = f2b(elu_f(a0 * S2[f] + C2[f]));
        o.y = f2b(elu_f(a1 * S2[f + 1] + C2[f + 1]));
        *reinterpret_cast<ushort2*>(&outb[(size_t)wid * 64 + f]) = o;
    }
}

// ---------------- launch ----------------
extern "C" void kernel_launch(void* const* d_in, const int* in_sizes, int n_in,
                              void* d_out, int out_size, void* d_ws, size_t ws_size,
                              hipStream_t stream)
{
    const float* x      = (const float*)d_in[0];
    const void*  ei     = d_in[1];
    const float* W1     = (const float*)d_in[2];
    const float* a_src1 = (const float*)d_in[3];
    const float* a_dst1 = (const float*)d_in[4];
    const float* b1     = (const float*)d_in[5];
    const float* W2     = (const float*)d_in[6];
    const float* a_src2 = (const float*)d_in[7];
    const float* a_dst2 = (const float*)d_in[8];
    const float* b2     = (const float*)d_in[9];
    const float* Wp     = (const float*)d_in[10];
    const float* bp     = (const float*)d_in[11];
    const float* g1 = (const float*)d_in[12], *be1 = (const float*)d_in[13];
    const float* m1 = (const float*)d_in[14], *v1  = (const float*)d_in[15];
    const float* g2 = (const float*)d_in[16], *be2 = (const float*)d_in[17];
    const float* m2 = (const float*)d_in[18], *v2  = (const float*)d_in[19];
    const float* g3 = (const float*)d_in[20], *be3 = (const float*)d_in[21];
    const float* m3 = (const float*)d_in[22], *v3  = (const float*)d_in[23];
    float* out = (float*)d_out;

    const int N  = in_sizes[0] / 128;
    const int E  = in_sizes[1] / 2;
    const int ET = E + N;

    char* base = (char*)d_ws;
    size_t off = 0;
    auto alloc = [&](size_t bytes) -> char* {
        char* p = base + off;
        off += (bytes + 255) & ~(size_t)255;
        return p;
    };
    float*  par     = (float*)alloc(1024 * 4);
    int*    flag64  = (int*)alloc(256);
    int*    mfma_ok = (int*)alloc(256);
    int*    bsum    = (int*)alloc(256);
    int*    bpre    = (int*)alloc(256);
    int*    rowptr  = (int*)alloc((size_t)(N + 1) * 4);
    int*    fillptr = (int*)alloc((size_t)(N + 1) * 4);
    int*    esrc    = (int*)alloc((size_t)ET * 4);
    float*  as1     = (float*)alloc((size_t)N * 8 * 4);
    float*  ad1     = (float*)alloc((size_t)N * 8 * 4);
    float*  as2     = (float*)alloc((size_t)N * 4);
    float*  ad2     = (float*)alloc((size_t)N * 4);
    ushort* wt1     = (ushort*)alloc(256 * 128 * 2);
    ushort* wt2     = (ushort*)alloc(64 * 256 * 2);
    ushort* wtp     = (ushort*)alloc(128 * 64 * 2);
    float*  walpha1 = (float*)alloc((size_t)ET * 8 * 4);
    float*  walpha2 = (float*)alloc((size_t)ET * 4);
    ushort* h1      = (ushort*)alloc((size_t)N * 256 * 2);
    ushort* h1b     = (ushort*)alloc((size_t)N * 256 * 2);
    ushort* h2      = (ushort*)alloc((size_t)N * 64 * 2);
    ushort* g2buf   = (ushort*)alloc((size_t)N * 64 * 2);

    // 0) setup
    detect_dtype_kernel<<<1, 256, 0, stream>>>(ei, min(2 * E, 4096), (long long)N, flag64);
    precompute_kernel<<<1, 256, 0, stream>>>(b1, b2, bp, g1, be1, m1, v1,
                                             g2, be2, m2, v2, g3, be3, m3, v3, par, mfma_ok);
    transpose_all_kernel<<<224, 256, 0, stream>>>(W1, W2, Wp, wt1, wt2, wtp);
    hipMemsetAsync(fillptr, 0, (N + 1) * sizeof(int), stream);

    // 1) CSR by dst (parallel scan)
    int ebl = (ET + 255) / 256;
    int nb = (N + 4095) / 4096;
    count_kernel<<<ebl, 256, 0, stream>>>(ei, E, N, flag64, fillptr);
    scan1_kernel<<<nb, 256, 0, stream>>>(fillptr, N, bsum);
    scan2_kernel<<<1, 64, 0, stream>>>(bsum, nb, bpre);
    scan3_kernel<<<nb, 256, 0, stream>>>(fillptr, N, bpre, nb, rowptr, fillptr);
    fill_kernel<<<ebl, 256, 0, stream>>>(ei, E, N, flag64, fillptr, esrc);

    // 2) layer 1
    int mb128 = (N + 127) / 128;
    int mb64  = (N + 63) / 64;
    int wbl   = (N + 3) / 4;
    mgemm_kernel<0, 0><<<dim3(mb128, 4), 256, 0, stream>>>(x, wt1, h1, N, 128, 256, nullptr, nullptr);
    check_kernel<<<1, 256, 0, stream>>>(x, W1, h1, N, mfma_ok);
    gemm64_kernel<0, 0><<<dim3(mb64, 4), 256, 0, stream>>>(x, W1, h1, N, 128, 256, nullptr, nullptr, mfma_ok);

    att1_kernel<<<wbl, 256, 0, stream>>>(h1, a_src1, a_dst1, as1, ad1, N);
    wden1_kernel<<<wbl, 256, 0, stream>>>(as1, ad1, rowptr, esrc, walpha1, N);
    agg1_kernel<<<wbl, 256, 0, stream>>>(h1, walpha1, rowptr, esrc, par, h1b, N);

    // 3) layer 2
    mgemm_kernel<1, 0><<<dim3(mb128, 1), 256, 0, stream>>>(h1b, wt2, h2, N, 256, 64, nullptr, nullptr);
    gemm64_kernel<1, 0><<<dim3(mb64, 1), 256, 0, stream>>>(h1b, W2, h2, N, 256, 64, nullptr, nullptr, mfma_ok);
    att2_kernel<<<wbl, 256, 0, stream>>>(h2, a_src2, a_dst2, as2, ad2, N);
    wden2_kernel<<<wbl, 256, 0, stream>>>(as2, ad2, rowptr, esrc, walpha2, N);
    agg2_kernel<<<wbl, 256, 0, stream>>>(h2, walpha2, rowptr, esrc, par, g2buf, N);

    // 4) projection + BN3 folded
    mgemm_kernel<1, 1><<<dim3(mb128, 2), 256, 0, stream>>>(g2buf, wtp, out, N, 64, 128, par + 640, par + 768);
    gemm64_kernel<1, 1><<<dim3(mb64, 2), 256, 0, stream>>>(g2buf, Wp, out, N, 64, 128, par + 640, par + 768, mfma_ok);
}

// Round 4
// 313.205 us; speedup vs baseline: 2.0021x; 1.1640x over previous
//
#include <hip/hip_runtime.h>
#include <math.h>

#define NEG_SLOPE 0.2f
#define BN_EPS 1e-5f

typedef __bf16 bf16x8 __attribute__((ext_vector_type(8)));
typedef float  f32x4  __attribute__((ext_vector_type(4)));

__device__ __forceinline__ float elu_f(float x){ return x > 0.f ? x : expm1f(x); }
__device__ __forceinline__ float lrelu_f(float x){ return x > 0.f ? x : NEG_SLOPE * x; }

__device__ __forceinline__ float b2f(ushort u){
    union { uint i; float f; } v; v.i = (uint)u << 16; return v.f;
}
__device__ __forceinline__ ushort f2b(float f){
    union { float f; uint i; } v; v.f = f;
    uint r = v.i + 0x7FFFu + ((v.i >> 16) & 1u);   // RTN-even
    return (ushort)(r >> 16);
}

// ---------------- fused setup: dtype detect + BN fold + weight transpose ----------------
// block 0: detect + precompute; blocks 1..224: transpose W1/W2/Wp to [n][k] bf16
__global__ void setup_kernel(const void* ei, int n_check, long long N, int* flag64,
    const float* __restrict__ W1, const float* __restrict__ W2, const float* __restrict__ Wp,
    ushort* __restrict__ wt1, ushort* __restrict__ wt2, ushort* __restrict__ wtp,
    const float* b1, const float* b2, const float* bp,
    const float* g1, const float* be1, const float* m1, const float* v1,
    const float* g2, const float* be2, const float* m2, const float* v2,
    const float* g3, const float* be3, const float* m3, const float* v3,
    float* par)
{
    int b = blockIdx.x, t = threadIdx.x;
    if (b == 0) {
        __shared__ int oks;
        if (t == 0) oks = 1;
        __syncthreads();
        const long long* p = (const long long*)ei;
        int ok = 1;
        for (int i = t; i < n_check; i += 256) {
            long long v = p[i];
            if (v < 0 || v >= N) ok = 0;
        }
        if (!ok) oks = 0;          // benign race
        __syncthreads();
        if (t == 0) *flag64 = oks;
        // BN fold: y = acc*S + C
        { float s = g1[t] * rsqrtf(v1[t] + BN_EPS); par[t] = s;        par[256 + t] = b1[t] * s + be1[t] - m1[t] * s; }
        if (t < 64)  { float s = g2[t] * rsqrtf(v2[t] + BN_EPS); par[512 + t] = s;  par[576 + t] = b2[t] * s + be2[t] - m2[t] * s; }
        if (t < 128) { float s = g3[t] * rsqrtf(v3[t] + BN_EPS); par[640 + t] = s;  par[768 + t] = bp[t] * s + be3[t] - m3[t] * s; }
    } else {
        int idx = (b - 1) * 256 + t;
        if (idx < 32768) {                       // W1: [128,256] -> wt1[n*128+k]
            int n = idx >> 7, k = idx & 127;
            wt1[idx] = f2b(W1[k * 256 + n]);
        } else if (idx < 49152) {                // W2: [256,64] -> wt2[n*256+k]
            int j = idx - 32768;
            int n = j >> 8, k = j & 255;
            wt2[j] = f2b(W2[k * 64 + n]);
        } else if (idx < 57344) {                // Wp: [64,128] -> wtp[n*64+k]
            int j = idx - 49152;
            int n = j >> 6, k = j & 63;
            wtp[j] = f2b(Wp[k * 128 + n]);
        }
    }
}

__device__ __forceinline__ void get_edge(const void* ei, int e, int E, int f64, int& s, int& d)
{
    if (e < E) {
        if (f64) { const long long* p = (const long long*)ei; s = (int)p[e]; d = (int)p[E + e]; }
        else     { const int*       p = (const int*)ei;       s = p[e];      d = p[E + e]; }
    } else {
        s = d = e - E;
    }
}

// ---------------- CSR build ----------------
__global__ void count_kernel(const void* ei, int E, int N, const int* flag64, int* deg)
{
    int i = blockIdx.x * blockDim.x + threadIdx.x;
    int ET = E + N;
    if (i >= ET) return;
    int s, d;
    get_edge(ei, i, E, *flag64, s, d);
    atomicAdd(&deg[d], 1);
}

__global__ void scan1_kernel(const int* __restrict__ deg, int N, int* __restrict__ bsum)
{
    int b = blockIdx.x, t = threadIdx.x;
    int base = b * 4096 + t * 16;
    int s = 0;
    #pragma unroll
    for (int k = 0; k < 16; k += 4) {
        int idx = base + k;
        if (idx + 3 < N) {
            int4 v = *reinterpret_cast<const int4*>(&deg[idx]);
            s += v.x + v.y + v.z + v.w;
        } else {
            for (int q = 0; q < 4; ++q) if (idx + q < N) s += deg[idx + q];
        }
    }
    #pragma unroll
    for (int off = 1; off < 64; off <<= 1) s += __shfl_xor(s, off);
    __shared__ int wsum[4];
    if ((t & 63) == 0) wsum[t >> 6] = s;
    __syncthreads();
    if (t == 0) bsum[b] = wsum[0] + wsum[1] + wsum[2] + wsum[3];
}

__global__ void scan2_kernel(const int* __restrict__ bsum, int nb, int* __restrict__ bpre)
{
    if (threadIdx.x == 0) {
        int r = 0;
        for (int i = 0; i < nb; ++i) { bpre[i] = r; r += bsum[i]; }
        bpre[nb] = r;
    }
}

__global__ void scan3_kernel(const int* __restrict__ deg, int N,
                             const int* __restrict__ bpre, int nb,
                             int* __restrict__ rowptr, int* __restrict__ fillptr)
{
    int b = blockIdx.x, t = threadIdx.x;
    int base = b * 4096 + t * 16;
    int loc[16];
    int s = 0;
    #pragma unroll
    for (int k = 0; k < 16; ++k) {
        int idx = base + k;
        int d = (idx < N) ? deg[idx] : 0;
        loc[k] = s; s += d;
    }
    int lane = t & 63;
    int incl = s;
    #pragma unroll
    for (int off = 1; off < 64; off <<= 1) {
        int v = __shfl_up(incl, off);
        if (lane >= off) incl += v;
    }
    __shared__ int wsum[4];
    if (lane == 63) wsum[t >> 6] = incl;
    __syncthreads();
    int woff = 0;
    int w = t >> 6;
    for (int i = 0; i < w; ++i) woff += wsum[i];
    int off0 = bpre[b] + woff + incl - s;
    #pragma unroll
    for (int k = 0; k < 16; ++k) {
        int idx = base + k;
        if (idx < N) { rowptr[idx] = off0 + loc[k]; fillptr[idx] = off0 + loc[k]; }
    }
    if (b == 0 && t == 0) rowptr[N] = bpre[nb];
}

__global__ void fill_kernel(const void* ei, int E, int N, const int* flag64,
                            int* fillptr, int* esrc)
{
    int i = blockIdx.x * blockDim.x + threadIdx.x;
    int ET = E + N;
    if (i >= ET) return;
    int s, d;
    get_edge(ei, i, E, *flag64, s, d);
    int pos = atomicAdd(&fillptr[d], 1);
    esrc[pos] = s;
}

// ---------------- MFMA bf16 GEMM: C[M,NC] = A[M,K] @ Bt[NC,K]^T ----------------
template<int ATYPE, int OMODE>
__global__ __launch_bounds__(256) void mgemm_kernel(const void* __restrict__ Ap,
    const ushort* __restrict__ Bt, void* __restrict__ Cp, int M, int K, int NC,
    const float* __restrict__ S, const float* __restrict__ Cc)
{
    const int BM = 128, LDA = 72;
    __shared__ __align__(16) ushort As[BM][LDA];
    __shared__ __align__(16) ushort Bs[64][LDA];
    int t = threadIdx.x;
    int m0 = blockIdx.x * BM, n0 = blockIdx.y * 64;
    int w = t >> 6, l = t & 63;
    int wm = w >> 1, wn = w & 1;
    int r16 = l & 15, kg = l >> 4;

    f32x4 acc[4][2];
    #pragma unroll
    for (int mi = 0; mi < 4; ++mi)
        #pragma unroll
        for (int ni = 0; ni < 2; ++ni)
            acc[mi][ni] = (f32x4){0.f, 0.f, 0.f, 0.f};

    for (int kb = 0; kb < K; kb += 64) {
        if (ATYPE == 0) {
            const float* A = (const float*)Ap;
            #pragma unroll
            for (int p = 0; p < 8; ++p) {
                int r = (t >> 4) + p * 16, c4 = (t & 15) * 4;
                int gm = m0 + r;
                float4 v = (gm < M) ? *reinterpret_cast<const float4*>(&A[(size_t)gm * K + kb + c4])
                                    : make_float4(0.f, 0.f, 0.f, 0.f);
                ushort4 u; u.x = f2b(v.x); u.y = f2b(v.y); u.z = f2b(v.z); u.w = f2b(v.w);
                *reinterpret_cast<ushort4*>(&As[r][c4]) = u;
            }
        } else {
            const ushort* A = (const ushort*)Ap;
            #pragma unroll
            for (int p = 0; p < 4; ++p) {
                int r = (t >> 3) + p * 32, c8 = (t & 7) * 8;
                int gm = m0 + r;
                uint4 v = (gm < M) ? *reinterpret_cast<const uint4*>(&A[(size_t)gm * K + kb + c8])
                                   : make_uint4(0u, 0u, 0u, 0u);
                *reinterpret_cast<uint4*>(&As[r][c8]) = v;
            }
        }
        #pragma unroll
        for (int p = 0; p < 2; ++p) {
            int r = (t >> 3) + p * 32, c8 = (t & 7) * 8;
            uint4 v = *reinterpret_cast<const uint4*>(&Bt[(size_t)(n0 + r) * K + kb + c8]);
            *reinterpret_cast<uint4*>(&Bs[r][c8]) = v;
        }
        __syncthreads();
        #pragma unroll
        for (int kk = 0; kk < 2; ++kk) {
            bf16x8 bB[2], bA[4];
            #pragma unroll
            for (int ni = 0; ni < 2; ++ni)
                bB[ni] = *reinterpret_cast<const bf16x8*>(&Bs[wn * 32 + ni * 16 + r16][kk * 32 + kg * 8]);
            #pragma unroll
            for (int mi = 0; mi < 4; ++mi)
                bA[mi] = *reinterpret_cast<const bf16x8*>(&As[wm * 64 + mi * 16 + r16][kk * 32 + kg * 8]);
            #pragma unroll
            for (int mi = 0; mi < 4; ++mi)
                #pragma unroll
                for (int ni = 0; ni < 2; ++ni)
                    acc[mi][ni] = __builtin_amdgcn_mfma_f32_16x16x32_bf16(bA[mi], bB[ni], acc[mi][ni], 0, 0, 0);
        }
        __syncthreads();
    }
    #pragma unroll
    for (int mi = 0; mi < 4; ++mi) {
        #pragma unroll
        for (int ni = 0; ni < 2; ++ni) {
            #pragma unroll
            for (int rg = 0; rg < 4; ++rg) {
                int gm = m0 + wm * 64 + mi * 16 + kg * 4 + rg;
                int gc = n0 + wn * 32 + ni * 16 + r16;
                if (gm < M) {
                    float v = acc[mi][ni][rg];
                    if (OMODE == 0) ((ushort*)Cp)[(size_t)gm * NC + gc] = f2b(v);
                    else            ((float*)Cp)[(size_t)gm * NC + gc] = v * S[gc] + Cc[gc];
                }
            }
        }
    }
}

// ---------------- attention coefficients ----------------
__global__ void att1_kernel(const ushort* __restrict__ h1,
                            const float* __restrict__ a_src, const float* __restrict__ a_dst,
                            float* __restrict__ as1, float* __restrict__ ad1, int N)
{
    int wid = (blockIdx.x * blockDim.x + threadIdx.x) >> 6;
    int lane = threadIdx.x & 63;
    if (wid >= N) return;
    ushort4 hv = *reinterpret_cast<const ushort4*>(&h1[(size_t)wid * 256 + lane * 4]);
    int f0 = lane * 4;
    float vx = b2f(hv.x), vy = b2f(hv.y), vz = b2f(hv.z), vw = b2f(hv.w);
    float s = vx * a_src[f0] + vy * a_src[f0 + 1] + vz * a_src[f0 + 2] + vw * a_src[f0 + 3];
    float d = vx * a_dst[f0] + vy * a_dst[f0 + 1] + vz * a_dst[f0 + 2] + vw * a_dst[f0 + 3];
    s += __shfl_xor(s, 1); s += __shfl_xor(s, 2); s += __shfl_xor(s, 4);
    d += __shfl_xor(d, 1); d += __shfl_xor(d, 2); d += __shfl_xor(d, 4);
    if ((lane & 7) == 0) {
        as1[wid * 8 + (lane >> 3)] = s;
        ad1[wid * 8 + (lane >> 3)] = d;
    }
}

__global__ void att2_kernel(const ushort* __restrict__ h2,
                            const float* __restrict__ a_src, const float* __restrict__ a_dst,
                            float* __restrict__ as2, float* __restrict__ ad2, int N)
{
    int wid = (blockIdx.x * blockDim.x + threadIdx.x) >> 6;
    int lane = threadIdx.x & 63;
    if (wid >= N) return;
    float v = b2f(h2[(size_t)wid * 64 + lane]);
    float s = v * a_src[lane];
    float d = v * a_dst[lane];
    #pragma unroll
    for (int off = 32; off; off >>= 1) {
        s += __shfl_down(s, off, 64);
        d += __shfl_down(d, off, 64);
    }
    if (lane == 0) { as2[wid] = s; ad2[wid] = d; }
}

// ---------------- aggregation layer 1: fused softmax, half-wave per edge ----------------
// phase A: per-head denominator (lane = j*8+h). phase B: half-wave owns 128 feats
// (16B/lane), edges i+half, stride 2, unrolled x2 -> 4 rows in flight per wave.
__global__ void agg1_kernel(const ushort* __restrict__ h1,
                            const float* __restrict__ as1, const float* __restrict__ ad1,
                            const int* __restrict__ rowptr, const int* __restrict__ esrc,
                            const float* __restrict__ par,
                            ushort* __restrict__ outb, int N)
{
    int wid = (blockIdx.x * blockDim.x + threadIdx.x) >> 6;
    int lane = threadIdx.x & 63;
    if (wid >= N) return;
    int beg = rowptr[wid], end = rowptr[wid + 1];

    // phase A: denominators (head h = lane&7, sub-edge j = lane>>3)
    int h = lane & 7;
    float ad_h = ad1[wid * 8 + h];
    float den = 0.f;
    for (int i = beg + (lane >> 3); i < end; i += 8)
        den += __expf(lrelu_f(as1[esrc[i] * 8 + h] + ad_h));
    den += __shfl_xor(den, 8, 64);
    den += __shfl_xor(den, 16, 64);
    den += __shfl_xor(den, 32, 64);
    float inv = 1.f / (den + 1e-16f);      // valid for head lane&7

    // phase B: half-wave per edge; lane li covers feats [li*8, li*8+8)
    int li = lane & 31, half = lane >> 5;
    int hh = li >> 2;                       // head of this lane's features
    float inv_h = __shfl(inv, hh, 64);
    float ad_hh = __shfl(ad_h, hh, 64);
    float acc[8] = {0.f, 0.f, 0.f, 0.f, 0.f, 0.f, 0.f, 0.f};

    auto edge1 = [&](int ii) {
        int src = esrc[ii];
        float al = __expf(lrelu_f(as1[src * 8 + hh] + ad_hh)) * inv_h;
        uint4 r = *reinterpret_cast<const uint4*>(&h1[(size_t)src * 256 + li * 8]);
        union { uint u; float f; } c0, c1;
        c0.u = r.x << 16; c1.u = r.x & 0xffff0000u; acc[0] += al * c0.f; acc[1] += al * c1.f;
        c0.u = r.y << 16; c1.u = r.y & 0xffff0000u; acc[2] += al * c0.f; acc[3] += al * c1.f;
        c0.u = r.z << 16; c1.u = r.z & 0xffff0000u; acc[4] += al * c0.f; acc[5] += al * c1.f;
        c0.u = r.w << 16; c1.u = r.w & 0xffff0000u; acc[6] += al * c0.f; acc[7] += al * c1.f;
    };
    int i = beg + half;
    for (; i + 2 < end; i += 4) { edge1(i); edge1(i + 2); }
    for (; i < end; i += 2) edge1(i);

    #pragma unroll
    for (int f = 0; f < 8; ++f) acc[f] += __shfl_xor(acc[f], 32, 64);
    if (half == 0) {
        int f0 = li * 8;
        const float* S1 = par;
        const float* C1 = par + 256;
        ushort o[8];
        #pragma unroll
        for (int f = 0; f < 8; ++f) o[f] = f2b(elu_f(acc[f] * S1[f0 + f] + C1[f0 + f]));
        uint4 pk;
        pk.x = (uint)o[0] | ((uint)o[1] << 16);
        pk.y = (uint)o[2] | ((uint)o[3] << 16);
        pk.z = (uint)o[4] | ((uint)o[5] << 16);
        pk.w = (uint)o[6] | ((uint)o[7] << 16);
        *reinterpret_cast<uint4*>(&outb[(size_t)wid * 256 + f0]) = pk;
    }
}

// ---------------- aggregation layer 2: fused softmax, half-wave per edge ----------------
__global__ void agg2_kernel(const ushort* __restrict__ h2,
                            const float* __restrict__ as2, const float* __restrict__ ad2,
                            const int* __restrict__ rowptr, const int* __restrict__ esrc,
                            const float* __restrict__ par,
                            ushort* __restrict__ outb, int N)
{
    int wid = (blockIdx.x * blockDim.x + threadIdx.x) >> 6;
    int lane = threadIdx.x & 63;
    if (wid >= N) return;
    int beg = rowptr[wid], end = rowptr[wid + 1];
    float ad = ad2[wid];
    float den = 0.f;
    for (int i = beg + lane; i < end; i += 64)
        den += __expf(lrelu_f(as2[esrc[i]] + ad));
    #pragma unroll
    for (int off = 1; off < 64; off <<= 1) den += __shfl_xor(den, off, 64);
    float inv = 1.f / (den + 1e-16f);

    int li = lane & 31, half = lane >> 5;
    float a0 = 0.f, a1 = 0.f;
    auto edge1 = [&](int ii) {
        int src = esrc[ii];
        float al = __expf(lrelu_f(as2[src] + ad)) * inv;
        uint hv = *reinterpret_cast<const uint*>(&h2[(size_t)src * 64 + li * 2]);
        union { uint u; float f; } c0, c1;
        c0.u = hv << 16; c1.u = hv & 0xffff0000u;
        a0 += al * c0.f; a1 += al * c1.f;
    };
    int i = beg + half;
    for (; i + 2 < end; i += 4) { edge1(i); edge1(i + 2); }
    for (; i < end; i += 2) edge1(i);

    a0 += __shfl_xor(a0, 32, 64);
    a1 += __shfl_xor(a1, 32, 64);
    if (half == 0) {
        int f = li * 2;
        const float* S2 = par + 512;
        const float* C2 = par + 576;
        ushort2 o;
        o.x = f2b(elu_f(a0 * S2[f] + C2[f]));
        o.y = f2b(elu_f(a1 * S2[f + 1] + C2[f + 1]));
        *reinterpret_cast<ushort2*>(&outb[(size_t)wid * 64 + f]) = o;
    }
}

// ---------------- launch ----------------
extern "C" void kernel_launch(void* const* d_in, const int* in_sizes, int n_in,
                              void* d_out, int out_size, void* d_ws, size_t ws_size,
                              hipStream_t stream)
{
    const float* x      = (const float*)d_in[0];
    const void*  ei     = d_in[1];
    const float* W1     = (const float*)d_in[2];
    const float* a_src1 = (const float*)d_in[3];
    const float* a_dst1 = (const float*)d_in[4];
    const float* b1     = (const float*)d_in[5];
    const float* W2     = (const float*)d_in[6];
    const float* a_src2 = (const float*)d_in[7];
    const float* a_dst2 = (const float*)d_in[8];
    const float* b2     = (const float*)d_in[9];
    const float* Wp     = (const float*)d_in[10];
    const float* bp     = (const float*)d_in[11];
    const float* g1 = (const float*)d_in[12], *be1 = (const float*)d_in[13];
    const float* m1 = (const float*)d_in[14], *v1  = (const float*)d_in[15];
    const float* g2 = (const float*)d_in[16], *be2 = (const float*)d_in[17];
    const float* m2 = (const float*)d_in[18], *v2  = (const float*)d_in[19];
    const float* g3 = (const float*)d_in[20], *be3 = (const float*)d_in[21];
    const float* m3 = (const float*)d_in[22], *v3  = (const float*)d_in[23];
    float* out = (float*)d_out;

    const int N  = in_sizes[0] / 128;
    const int E  = in_sizes[1] / 2;
    const int ET = E + N;

    char* base = (char*)d_ws;
    size_t off = 0;
    auto alloc = [&](size_t bytes) -> char* {
        char* p = base + off;
        off += (bytes + 255) & ~(size_t)255;
        return p;
    };
    float*  par     = (float*)alloc(1024 * 4);
    int*    flag64  = (int*)alloc(256);
    int*    bsum    = (int*)alloc(256);
    int*    bpre    = (int*)alloc(256);
    int*    rowptr  = (int*)alloc((size_t)(N + 1) * 4);
    int*    fillptr = (int*)alloc((size_t)(N + 1) * 4);
    int*    esrc    = (int*)alloc((size_t)ET * 4);
    float*  as1     = (float*)alloc((size_t)N * 8 * 4);
    float*  ad1     = (float*)alloc((size_t)N * 8 * 4);
    float*  as2     = (float*)alloc((size_t)N * 4);
    float*  ad2     = (float*)alloc((size_t)N * 4);
    ushort* wt1     = (ushort*)alloc(256 * 128 * 2);
    ushort* wt2     = (ushort*)alloc(64 * 256 * 2);
    ushort* wtp     = (ushort*)alloc(128 * 64 * 2);
    ushort* h1      = (ushort*)alloc((size_t)N * 256 * 2);
    ushort* h1b     = (ushort*)alloc((size_t)N * 256 * 2);
    ushort* h2      = (ushort*)alloc((size_t)N * 64 * 2);
    ushort* g2buf   = (ushort*)alloc((size_t)N * 64 * 2);

    // 0) fused setup
    setup_kernel<<<225, 256, 0, stream>>>(ei, min(2 * E, 4096), (long long)N, flag64,
        W1, W2, Wp, wt1, wt2, wtp,
        b1, b2, bp, g1, be1, m1, v1, g2, be2, m2, v2, g3, be3, m3, v3, par);
    hipMemsetAsync(fillptr, 0, (N + 1) * sizeof(int), stream);

    // 1) CSR by dst
    int ebl = (ET + 255) / 256;
    int nb = (N + 4095) / 4096;
    count_kernel<<<ebl, 256, 0, stream>>>(ei, E, N, flag64, fillptr);
    scan1_kernel<<<nb, 256, 0, stream>>>(fillptr, N, bsum);
    scan2_kernel<<<1, 64, 0, stream>>>(bsum, nb, bpre);
    scan3_kernel<<<nb, 256, 0, stream>>>(fillptr, N, bpre, nb, rowptr, fillptr);
    fill_kernel<<<ebl, 256, 0, stream>>>(ei, E, N, flag64, fillptr, esrc);

    // 2) layer 1
    int mb128 = (N + 127) / 128;
    int wbl   = (N + 3) / 4;
    mgemm_kernel<0, 0><<<dim3(mb128, 4), 256, 0, stream>>>(x, wt1, h1, N, 128, 256, nullptr, nullptr);
    att1_kernel<<<wbl, 256, 0, stream>>>(h1, a_src1, a_dst1, as1, ad1, N);
    agg1_kernel<<<wbl, 256, 0, stream>>>(h1, as1, ad1, rowptr, esrc, par, h1b, N);

    // 3) layer 2
    mgemm_kernel<1, 0><<<dim3(mb128, 1), 256, 0, stream>>>(h1b, wt2, h2, N, 256, 64, nullptr, nullptr);
    att2_kernel<<<wbl, 256, 0, stream>>>(h2, a_src2, a_dst2, as2, ad2, N);
    agg2_kernel<<<wbl, 256, 0, stream>>>(h2, as2, ad2, rowptr, esrc, par, g2buf, N);

    // 4) projection + BN3 folded
    mgemm_kernel<1, 1><<<dim3(mb128, 2), 256, 0, stream>>>(g2buf, wtp, out, N, 64, 128, par + 640, par + 768);
}